// Round 1
// baseline (126.176 us; speedup 1.0000x reference)
//
#include <hip/hip_runtime.h>
#include <math.h>

#define EPSF 1e-7f
#define BETA_F 0.08838834764831845f

// ---------------- workspace layout (float offsets) ----------------
// Qs    : 1024*128            @ 0
// Qt    : 1024                @ 131072
// LQ    : 1024                @ 132096
// KT    : 128*2048            @ 133120   (transposed: [d][j])
// Kt    : 2048                @ 395264
// VT    : 128*2048            @ 397312   (transposed)
// Vrow  : 2048*128            @ 659456   (row-major)
// Vt    : 2048                @ 921600
// LV    : 2048                @ 923648
// part  : 1024*4*132          @ 925696
#define WS_QS    0
#define WS_QT    131072
#define WS_LQ    132096
#define WS_KT    133120
#define WS_KTIME 395264
#define WS_VT    397312
#define WS_VROW  659456
#define WS_VTIME 921600
#define WS_LV    923648
#define WS_PART  925696

__device__ __forceinline__ float wave_sum(float v) {
#pragma unroll
  for (int off = 32; off > 0; off >>= 1) v += __shfl_xor(v, off);
  return v;
}
__device__ __forceinline__ float wave_max(float v) {
#pragma unroll
  for (int off = 32; off > 0; off >>= 1) v = fmaxf(v, __shfl_xor(v, off));
  return v;
}

// ---------------- prep Q: tangent map of raw queries ----------------
__global__ void prep_q(const float* __restrict__ queries, float* __restrict__ Qs,
                       float* __restrict__ Qt, float* __restrict__ LQ) {
  int i = blockIdx.x;
  int lane = threadIdx.x;  // 64
  float2 r = ((const float2*)(queries + (size_t)i * 128))[lane];
  float s2 = wave_sum(r.x * r.x + r.y * r.y);
  float n = sqrtf(s2);
  float f = fminf(3.5f / (n + EPSF), 1.0f);
  float t = fmaxf(n * f, EPSF);
  float coef = sinhf(t) / t * f;
  float ch = coshf(t);
  ((float2*)(Qs + (size_t)i * 128))[lane] = make_float2(coef * r.x, coef * r.y);
  if (lane == 0) {
    Qt[i] = ch;
    LQ[i] = coef * coef * s2 - ch * ch;
  }
}

// ---------------- prep K: keys@W_K -> tangent map -> KT, Kt ----------------
__global__ void prep_k(const float* __restrict__ keys, const float* __restrict__ WK,
                       float* __restrict__ KT, float* __restrict__ Kt) {
  int j0 = blockIdx.x * 4;
  int c = threadIdx.x;  // 128
  __shared__ __align__(16) float rows[4 * 512];
  for (int idx = c; idx < 2048; idx += 128) rows[idx] = keys[(size_t)j0 * 512 + idx];
  __syncthreads();
  float a0 = 0, a1 = 0, a2 = 0, a3 = 0;
#pragma unroll 8
  for (int l = 0; l < 512; ++l) {
    float w = WK[l * 128 + c];
    a0 = fmaf(rows[l], w, a0);
    a1 = fmaf(rows[512 + l], w, a1);
    a2 = fmaf(rows[1024 + l], w, a2);
    a3 = fmaf(rows[1536 + l], w, a3);
  }
  __shared__ __align__(16) float4 red[128];
  red[c] = make_float4(a0 * a0, a1 * a1, a2 * a2, a3 * a3);
  __syncthreads();
  for (int s = 64; s > 0; s >>= 1) {
    if (c < s) {
      float4 x = red[c], y = red[c + s];
      red[c] = make_float4(x.x + y.x, x.y + y.y, x.z + y.z, x.w + y.w);
    }
    __syncthreads();
  }
  float4 S = red[0];
  float Ss[4] = {S.x, S.y, S.z, S.w};
  float acc[4] = {a0, a1, a2, a3};
  float4 outv;
  float* op = (float*)&outv;
#pragma unroll
  for (int r = 0; r < 4; ++r) {
    float n = sqrtf(Ss[r]);
    float f = fminf(3.5f / (n + EPSF), 1.0f);
    float t = fmaxf(n * f, EPSF);
    float coef = sinhf(t) / t * f;
    op[r] = coef * acc[r];
    if (c == r) Kt[j0 + r] = coshf(t);
  }
  ((float4*)(KT + (size_t)c * 2048 + j0))[0] = outv;
}

// ---------------- prep V: (values@W_K)@W_V -> tangent map ----------------
__global__ void prep_v(const float* __restrict__ values, const float* __restrict__ WK,
                       const float* __restrict__ WV, float* __restrict__ VT,
                       float* __restrict__ Vrow, float* __restrict__ Vt,
                       float* __restrict__ LV) {
  int j0 = blockIdx.x * 4;
  int c = threadIdx.x;  // 128
  __shared__ __align__(16) float rows[4 * 512];
  __shared__ __align__(16) float vp1[4 * 128];
  for (int idx = c; idx < 2048; idx += 128) rows[idx] = values[(size_t)j0 * 512 + idx];
  __syncthreads();
  float a0 = 0, a1 = 0, a2 = 0, a3 = 0;
#pragma unroll 8
  for (int l = 0; l < 512; ++l) {
    float w = WK[l * 128 + c];
    a0 = fmaf(rows[l], w, a0);
    a1 = fmaf(rows[512 + l], w, a1);
    a2 = fmaf(rows[1024 + l], w, a2);
    a3 = fmaf(rows[1536 + l], w, a3);
  }
  vp1[c] = a0; vp1[128 + c] = a1; vp1[256 + c] = a2; vp1[384 + c] = a3;
  __syncthreads();
  float b0 = 0, b1 = 0, b2 = 0, b3 = 0;
#pragma unroll 8
  for (int l = 0; l < 128; ++l) {
    float w = WV[l * 128 + c];
    b0 = fmaf(vp1[l], w, b0);
    b1 = fmaf(vp1[128 + l], w, b1);
    b2 = fmaf(vp1[256 + l], w, b2);
    b3 = fmaf(vp1[384 + l], w, b3);
  }
  __shared__ __align__(16) float4 red[128];
  red[c] = make_float4(b0 * b0, b1 * b1, b2 * b2, b3 * b3);
  __syncthreads();
  for (int s = 64; s > 0; s >>= 1) {
    if (c < s) {
      float4 x = red[c], y = red[c + s];
      red[c] = make_float4(x.x + y.x, x.y + y.y, x.z + y.z, x.w + y.w);
    }
    __syncthreads();
  }
  float4 S = red[0];
  float Ss[4] = {S.x, S.y, S.z, S.w};
  float acc[4] = {b0, b1, b2, b3};
  float4 outv;
  float* op = (float*)&outv;
#pragma unroll
  for (int r = 0; r < 4; ++r) {
    float n = sqrtf(Ss[r]);
    float f = fminf(3.5f / (n + EPSF), 1.0f);
    float t = fmaxf(n * f, EPSF);
    float coef = sinhf(t) / t * f;
    float sv = coef * acc[r];
    op[r] = sv;
    Vrow[(size_t)(j0 + r) * 128 + c] = sv;
    if (c == r) {
      float ch = coshf(t);
      Vt[j0 + r] = ch;
      LV[j0 + r] = coef * coef * Ss[r] - ch * ch;
    }
  }
  ((float4*)(VT + (size_t)c * 2048 + j0))[0] = outv;
}

// ---------------- fused pair phase: 8 queries/block, 4 j-splits ----------------
__launch_bounds__(256, 2)
__global__ void attn(const float* __restrict__ Qs, const float* __restrict__ Qt,
                     const float* __restrict__ LQ, const float* __restrict__ KT,
                     const float* __restrict__ Kt, const float* __restrict__ VT,
                     const float* __restrict__ Vrow, const float* __restrict__ Vt,
                     const float* __restrict__ LV, float* __restrict__ part) {
  int G = blockIdx.x >> 2;   // query group of 8
  int S = blockIdx.x & 3;    // j-split
  int tid = threadIdx.x, lane = tid & 63, wv = tid >> 6;
  __shared__ __align__(16) float qsh[8 * 128];
  __shared__ float qt8[8], lq8[8];
  __shared__ __align__(16) float g_sh[4][8][64];
  __shared__ __align__(16) float mrg[4][8][132];

  for (int idx = tid; idx < 1024; idx += 256) qsh[idx] = Qs[(size_t)G * 1024 + idx];
  if (tid < 8) { qt8[tid] = Qt[G * 8 + tid]; lq8[tid] = LQ[G * 8 + tid]; }
  __syncthreads();

  float m8[8], l8[8], Tc8[8], Tt8[8], T2x[8], T2y[8];
#pragma unroll
  for (int q = 0; q < 8; ++q) {
    m8[q] = -INFINITY; l8[q] = 0; Tc8[q] = 0; Tt8[q] = 0; T2x[q] = 0; T2y[q] = 0;
  }

  for (int tt = 0; tt < 2; ++tt) {
    int tile = S * 8 + wv + tt * 4;
    int jb = tile * 64;
    int j = jb + lane;
    float ss[8], cc[8];
#pragma unroll
    for (int q = 0; q < 8; ++q) { ss[q] = 0; cc[q] = 0; }
    const float* KTp = KT + j;
    const float* VTp = VT + j;
#pragma unroll 2
    for (int db = 0; db < 32; ++db) {
      float k0 = KTp[(4 * db + 0) * 2048];
      float k1 = KTp[(4 * db + 1) * 2048];
      float k2 = KTp[(4 * db + 2) * 2048];
      float k3 = KTp[(4 * db + 3) * 2048];
      float v0 = VTp[(4 * db + 0) * 2048];
      float v1 = VTp[(4 * db + 1) * 2048];
      float v2 = VTp[(4 * db + 2) * 2048];
      float v3 = VTp[(4 * db + 3) * 2048];
#pragma unroll
      for (int q = 0; q < 8; ++q) {
        float4 qv = ((const float4*)(qsh + q * 128))[db];
        ss[q] = fmaf(qv.w, k3, fmaf(qv.z, k2, fmaf(qv.y, k1, fmaf(qv.x, k0, ss[q]))));
        cc[q] = fmaf(qv.w, v3, fmaf(qv.z, v2, fmaf(qv.y, v1, fmaf(qv.x, v0, cc[q]))));
      }
    }
    float ktj = Kt[j], vtj = Vt[j], lvj = LV[j];
#pragma unroll
    for (int q = 0; q < 8; ++q) {
      float sim = ss[q] - qt8[q] * ktj;
      float c = cc[q] - qt8[q] * vtj;
      float logit = -BETA_F * sim;
      float tm = wave_max(logit);
      float mn = fmaxf(m8[q], tm);
      float sca = expf(m8[q] - mn);
      float e = expf(logit - mn);
      float mc = fmaxf(-c, 1.0f + EPSF);
      float dist = acoshf(mc);
      float den = sqrtf(fmaxf(lvj + (2.0f + lq8[q]) * c * c, EPSF));
      float g = e * dist / den;
      l8[q] = l8[q] * sca + e;
      Tc8[q] = Tc8[q] * sca + g * c;
      Tt8[q] = Tt8[q] * sca + g * vtj;
      T2x[q] *= sca;
      T2y[q] *= sca;
      m8[q] = mn;
      g_sh[wv][q][lane] = g;
    }
    const float2* Vr = (const float2*)(Vrow + (size_t)jb * 128);
#pragma unroll 2
    for (int jj = 0; jj < 64; jj += 2) {
      float2 va = Vr[jj * 64 + lane];
      float2 vb = Vr[(jj + 1) * 64 + lane];
#pragma unroll
      for (int q = 0; q < 8; ++q) {
        float2 g2 = ((const float2*)g_sh[wv][q])[jj >> 1];
        T2x[q] = fmaf(g2.x, va.x, T2x[q]);
        T2y[q] = fmaf(g2.x, va.y, T2y[q]);
        T2x[q] = fmaf(g2.y, vb.x, T2x[q]);
        T2y[q] = fmaf(g2.y, vb.y, T2y[q]);
      }
    }
  }

  // wave-reduce per-lane scalar partials, stash to LDS
#pragma unroll
  for (int q = 0; q < 8; ++q) {
    l8[q] = wave_sum(l8[q]);
    Tc8[q] = wave_sum(Tc8[q]);
    Tt8[q] = wave_sum(Tt8[q]);
    mrg[wv][q][2 * lane] = T2x[q];
    mrg[wv][q][2 * lane + 1] = T2y[q];
    if (lane == 0) {
      mrg[wv][q][128] = m8[q];
      mrg[wv][q][129] = l8[q];
      mrg[wv][q][130] = Tc8[q];
      mrg[wv][q][131] = Tt8[q];
    }
  }
  __syncthreads();

  // merge the 4 waves; wave wv handles queries 2wv, 2wv+1
#pragma unroll
  for (int qq = 0; qq < 2; ++qq) {
    int q = wv * 2 + qq;
    float w0 = mrg[0][q][128], w1 = mrg[1][q][128], w2 = mrg[2][q][128], w3 = mrg[3][q][128];
    float mM = fmaxf(fmaxf(w0, w1), fmaxf(w2, w3));
    float s0 = expf(w0 - mM), s1 = expf(w1 - mM), s2 = expf(w2 - mM), s3 = expf(w3 - mM);
    float lM = s0 * mrg[0][q][129] + s1 * mrg[1][q][129] + s2 * mrg[2][q][129] + s3 * mrg[3][q][129];
    float TcM = s0 * mrg[0][q][130] + s1 * mrg[1][q][130] + s2 * mrg[2][q][130] + s3 * mrg[3][q][130];
    float TtM = s0 * mrg[0][q][131] + s1 * mrg[1][q][131] + s2 * mrg[2][q][131] + s3 * mrg[3][q][131];
    float tx = s0 * mrg[0][q][2 * lane] + s1 * mrg[1][q][2 * lane] +
               s2 * mrg[2][q][2 * lane] + s3 * mrg[3][q][2 * lane];
    float ty = s0 * mrg[0][q][2 * lane + 1] + s1 * mrg[1][q][2 * lane + 1] +
               s2 * mrg[2][q][2 * lane + 1] + s3 * mrg[3][q][2 * lane + 1];
    float* P = part + ((size_t)(G * 8 + q) * 4 + S) * 132;
    ((float2*)P)[lane] = make_float2(tx, ty);
    if (lane == 0) {
      P[128] = mM; P[129] = lM; P[130] = TcM; P[131] = TtM;
    }
  }
}

// ---------------- merge splits + hyperbolic epilogue ----------------
__global__ void merge_fin(const float* __restrict__ part, const float* __restrict__ Qs,
                          const float* __restrict__ Qt, float* __restrict__ out) {
  int qi = blockIdx.x;
  int lane = threadIdx.x;  // 64
  const float* P0 = part + (size_t)qi * 4 * 132;
  float w0 = P0[128], w1 = P0[132 + 128], w2 = P0[264 + 128], w3 = P0[396 + 128];
  float mM = fmaxf(fmaxf(w0, w1), fmaxf(w2, w3));
  float s0 = expf(w0 - mM), s1 = expf(w1 - mM), s2 = expf(w2 - mM), s3 = expf(w3 - mM);
  float l = s0 * P0[129] + s1 * P0[132 + 129] + s2 * P0[264 + 129] + s3 * P0[396 + 129];
  float Tc = s0 * P0[130] + s1 * P0[132 + 130] + s2 * P0[264 + 130] + s3 * P0[396 + 130];
  float Tt = s0 * P0[131] + s1 * P0[132 + 131] + s2 * P0[264 + 131] + s3 * P0[396 + 131];
  float tx = s0 * P0[2 * lane] + s1 * P0[132 + 2 * lane] + s2 * P0[264 + 2 * lane] +
             s3 * P0[396 + 2 * lane];
  float ty = s0 * P0[2 * lane + 1] + s1 * P0[132 + 2 * lane + 1] +
             s2 * P0[264 + 2 * lane + 1] + s3 * P0[396 + 2 * lane + 1];
  float2 q2 = ((const float2*)(Qs + (size_t)qi * 128))[lane];
  float qt = Qt[qi];
  float invl = 1.0f / l;
  float Tmx = (tx + Tc * q2.x) * invl;
  float Tmy = (ty + Tc * q2.y) * invl;
  float Tmt = (Tt + Tc * qt) * invl;
  float sp2 = wave_sum(Tmx * Tmx + Tmy * Tmy);
  float LT = sp2 - Tmt * Tmt;
  float un = sqrtf(fmaxf(LT, EPSF));
  float ch = coshf(un);
  float shv = sinhf(un) / un;
  float zx = ch * q2.x + shv * Tmx;
  float zy = ch * q2.y + shv * Tmy;
  float zt = ch * qt + shv * Tmt;
  float zn2 = wave_sum(zx * zx + zy * zy);
  float nz = fmaxf(sqrtf(zn2), EPSF);
  float dist = acoshf(fmaxf(zt, 1.0f + EPSF));
  float sc = dist / nz;
  ((float2*)(out + (size_t)qi * 128))[lane] = make_float2(sc * zx, sc * zy);
}

extern "C" void kernel_launch(void* const* d_in, const int* in_sizes, int n_in,
                              void* d_out, int out_size, void* d_ws, size_t ws_size,
                              hipStream_t stream) {
  const float* queries = (const float*)d_in[0];
  const float* keys = (const float*)d_in[1];
  const float* values = (const float*)d_in[2];
  const float* WK = (const float*)d_in[3];
  const float* WV = (const float*)d_in[4];
  float* ws = (float*)d_ws;
  float* Qs = ws + WS_QS;
  float* Qt_ = ws + WS_QT;
  float* LQ = ws + WS_LQ;
  float* KT = ws + WS_KT;
  float* Kt_ = ws + WS_KTIME;
  float* VT = ws + WS_VT;
  float* Vrow = ws + WS_VROW;
  float* Vt_ = ws + WS_VTIME;
  float* LV = ws + WS_LV;
  float* part = ws + WS_PART;
  float* out = (float*)d_out;

  prep_q<<<1024, 64, 0, stream>>>(queries, Qs, Qt_, LQ);
  prep_k<<<512, 128, 0, stream>>>(keys, WK, KT, Kt_);
  prep_v<<<512, 128, 0, stream>>>(values, WK, WV, VT, Vrow, Vt_, LV);
  attn<<<512, 256, 0, stream>>>(Qs, Qt_, LQ, KT, Kt_, VT, Vrow, Vt_, LV, part);
  merge_fin<<<1024, 64, 0, stream>>>(part, Qs, Qt_, out);
}

// Round 3
// 86.367 us; speedup vs baseline: 1.4609x; 1.4609x over previous
//
#include <hip/hip_runtime.h>
#include <math.h>

#define EPSF 1e-7f
#define BETA_F 0.08838834764831845f

typedef __attribute__((ext_vector_type(8))) short bf8_t;   // 8 x bf16 bits
typedef __attribute__((ext_vector_type(4))) float f32x4;

// ---------------- workspace layout (float offsets) ----------------
#define WS_QS    0          // 1024*128 f32 (for epilogue)
#define WS_QT    131072     // 1024
#define WS_LQ    132096     // 1024
#define WS_KT    133120     // 2048
#define WS_VT    135168     // 2048
#define WS_LV    137216     // 2048
#define WS_QHI   139264     // 1024*128 bf16 = 65536 fslots
#define WS_QLO   204800
#define WS_KHI   270336     // 2048*128 bf16 = 131072 fslots (row-major [j][d])
#define WS_KLO   401408
#define WS_VHI   532480     // row-major [j][d]
#define WS_VLO   663552
#define WS_VTHI  794624     // transposed [d][j]
#define WS_VTLO  925696
#define WS_PART  1056768    // 1024 * 8 * 132

__device__ __forceinline__ float wave_sum(float v) {
#pragma unroll
  for (int off = 32; off > 0; off >>= 1) v += __shfl_xor(v, off);
  return v;
}
__device__ __forceinline__ unsigned short f2bf(float x) {
  unsigned int u = __float_as_uint(x);
  u += 0x7FFFu + ((u >> 16) & 1u);
  return (unsigned short)(u >> 16);
}
__device__ __forceinline__ float bf2f(unsigned short h) {
  return __uint_as_float(((unsigned int)h) << 16);
}
__device__ __forceinline__ bf8_t ld8(const unsigned short* p) {
  return __builtin_bit_cast(bf8_t, *(const uint4*)p);
}
__device__ __forceinline__ f32x4 mfma16(bf8_t a, bf8_t b, f32x4 c) {
  return __builtin_amdgcn_mfma_f32_16x16x32_bf16(a, b, c, 0, 0, 0);
}

// ---------------- prep Q ----------------
__global__ void prep_q(const float* __restrict__ queries, float* __restrict__ Qs,
                       float* __restrict__ qt, float* __restrict__ lqv,
                       unsigned int* __restrict__ Qhi, unsigned int* __restrict__ Qlo) {
  int i = blockIdx.x;
  int lane = threadIdx.x;  // 64
  float2 r = ((const float2*)(queries + (size_t)i * 128))[lane];
  float s2 = wave_sum(r.x * r.x + r.y * r.y);
  float n = sqrtf(s2);
  float f = fminf(3.5f / (n + EPSF), 1.0f);
  float t = fmaxf(n * f, EPSF);
  float coef = sinhf(t) / t * f;
  float ch = coshf(t);
  float x0 = coef * r.x, x1 = coef * r.y;
  ((float2*)(Qs + (size_t)i * 128))[lane] = make_float2(x0, x1);
  unsigned short h0 = f2bf(x0), h1 = f2bf(x1);
  Qhi[i * 64 + lane] = (unsigned)h0 | ((unsigned)h1 << 16);
  unsigned short g0 = f2bf(x0 - bf2f(h0)), g1 = f2bf(x1 - bf2f(h1));
  Qlo[i * 64 + lane] = (unsigned)g0 | ((unsigned)g1 << 16);
  if (lane == 0) {
    qt[i] = ch;
    lqv[i] = coef * coef * s2 - ch * ch;
  }
}

// ---------------- prep K: keys@W_K -> tangent -> bf16 hi/lo row-major ----------------
__global__ void prep_k(const float* __restrict__ keys, const float* __restrict__ WK,
                       unsigned short* __restrict__ Khi, unsigned short* __restrict__ Klo,
                       float* __restrict__ kt) {
  int j0 = blockIdx.x * 4;
  int c = threadIdx.x;  // 128
  __shared__ __align__(16) float rows[4 * 512];
  for (int idx = c; idx < 2048; idx += 128) rows[idx] = keys[(size_t)j0 * 512 + idx];
  __syncthreads();
  float a0 = 0, a1 = 0, a2 = 0, a3 = 0;
#pragma unroll 8
  for (int l = 0; l < 512; ++l) {
    float w = WK[l * 128 + c];
    a0 = fmaf(rows[l], w, a0);
    a1 = fmaf(rows[512 + l], w, a1);
    a2 = fmaf(rows[1024 + l], w, a2);
    a3 = fmaf(rows[1536 + l], w, a3);
  }
  __shared__ __align__(16) float4 red[128];
  red[c] = make_float4(a0 * a0, a1 * a1, a2 * a2, a3 * a3);
  __syncthreads();
  for (int s = 64; s > 0; s >>= 1) {
    if (c < s) {
      float4 x = red[c], y = red[c + s];
      red[c] = make_float4(x.x + y.x, x.y + y.y, x.z + y.z, x.w + y.w);
    }
    __syncthreads();
  }
  float4 S = red[0];
  float Ss[4] = {S.x, S.y, S.z, S.w};
  float acc[4] = {a0, a1, a2, a3};
  __shared__ __align__(16) float shT[4][128];
#pragma unroll
  for (int r = 0; r < 4; ++r) {
    float n = sqrtf(Ss[r]);
    float f = fminf(3.5f / (n + EPSF), 1.0f);
    float t = fmaxf(n * f, EPSF);
    float coef = sinhf(t) / t * f;
    shT[r][c] = coef * acc[r];
    if (c == r) kt[j0 + r] = coshf(t);
  }
  __syncthreads();
  int rr = c >> 5, cc = (c & 31) * 4;
  const float* src = &shT[rr][cc];
  float x0 = src[0], x1 = src[1], x2 = src[2], x3 = src[3];
  unsigned short h0 = f2bf(x0), h1 = f2bf(x1), h2 = f2bf(x2), h3 = f2bf(x3);
  unsigned short g0 = f2bf(x0 - bf2f(h0)), g1 = f2bf(x1 - bf2f(h1));
  unsigned short g2 = f2bf(x2 - bf2f(h2)), g3 = f2bf(x3 - bf2f(h3));
  *(uint2*)(Khi + (size_t)(j0 + rr) * 128 + cc) =
      make_uint2((unsigned)h0 | ((unsigned)h1 << 16), (unsigned)h2 | ((unsigned)h3 << 16));
  *(uint2*)(Klo + (size_t)(j0 + rr) * 128 + cc) =
      make_uint2((unsigned)g0 | ((unsigned)g1 << 16), (unsigned)g2 | ((unsigned)g3 << 16));
}

// ---------------- prep V: (values@W_K)@W_V -> tangent -> bf16 hi/lo both layouts ----------------
__global__ void prep_v(const float* __restrict__ values, const float* __restrict__ WK,
                       const float* __restrict__ WV,
                       unsigned short* __restrict__ Vhi, unsigned short* __restrict__ Vlo,
                       unsigned short* __restrict__ VThi, unsigned short* __restrict__ VTlo,
                       float* __restrict__ vt, float* __restrict__ lv) {
  int j0 = blockIdx.x * 4;
  int c = threadIdx.x;  // 128
  __shared__ __align__(16) float rows[4 * 512];
  __shared__ __align__(16) float vp1[4 * 128];
  for (int idx = c; idx < 2048; idx += 128) rows[idx] = values[(size_t)j0 * 512 + idx];
  __syncthreads();
  float a0 = 0, a1 = 0, a2 = 0, a3 = 0;
#pragma unroll 8
  for (int l = 0; l < 512; ++l) {
    float w = WK[l * 128 + c];
    a0 = fmaf(rows[l], w, a0);
    a1 = fmaf(rows[512 + l], w, a1);
    a2 = fmaf(rows[1024 + l], w, a2);
    a3 = fmaf(rows[1536 + l], w, a3);
  }
  vp1[c] = a0; vp1[128 + c] = a1; vp1[256 + c] = a2; vp1[384 + c] = a3;
  __syncthreads();
  float b0 = 0, b1 = 0, b2 = 0, b3 = 0;
#pragma unroll 8
  for (int l = 0; l < 128; ++l) {
    float w = WV[l * 128 + c];
    b0 = fmaf(vp1[l], w, b0);
    b1 = fmaf(vp1[128 + l], w, b1);
    b2 = fmaf(vp1[256 + l], w, b2);
    b3 = fmaf(vp1[384 + l], w, b3);
  }
  __shared__ __align__(16) float4 red[128];
  red[c] = make_float4(b0 * b0, b1 * b1, b2 * b2, b3 * b3);
  __syncthreads();
  for (int s = 64; s > 0; s >>= 1) {
    if (c < s) {
      float4 x = red[c], y = red[c + s];
      red[c] = make_float4(x.x + y.x, x.y + y.y, x.z + y.z, x.w + y.w);
    }
    __syncthreads();
  }
  float4 S = red[0];
  float Ss[4] = {S.x, S.y, S.z, S.w};
  float acc[4] = {b0, b1, b2, b3};
  __shared__ __align__(16) float shT[4][128];
  unsigned short th[4], tl[4];
#pragma unroll
  for (int r = 0; r < 4; ++r) {
    float n = sqrtf(Ss[r]);
    float f = fminf(3.5f / (n + EPSF), 1.0f);
    float t = fmaxf(n * f, EPSF);
    float coef = sinhf(t) / t * f;
    float sv = coef * acc[r];
    shT[r][c] = sv;
    th[r] = f2bf(sv);
    tl[r] = f2bf(sv - bf2f(th[r]));
    if (c == r) {
      float ch = coshf(t);
      vt[j0 + r] = ch;
      lv[j0 + r] = coef * coef * Ss[r] - ch * ch;
    }
  }
  // transposed store: column c, rows j0..j0+3 contiguous
  *(uint2*)(VThi + (size_t)c * 2048 + j0) =
      make_uint2((unsigned)th[0] | ((unsigned)th[1] << 16), (unsigned)th[2] | ((unsigned)th[3] << 16));
  *(uint2*)(VTlo + (size_t)c * 2048 + j0) =
      make_uint2((unsigned)tl[0] | ((unsigned)tl[1] << 16), (unsigned)tl[2] | ((unsigned)tl[3] << 16));
  __syncthreads();
  int rr = c >> 5, cc = (c & 31) * 4;
  const float* src = &shT[rr][cc];
  float x0 = src[0], x1 = src[1], x2 = src[2], x3 = src[3];
  unsigned short h0 = f2bf(x0), h1 = f2bf(x1), h2 = f2bf(x2), h3 = f2bf(x3);
  unsigned short g0 = f2bf(x0 - bf2f(h0)), g1 = f2bf(x1 - bf2f(h1));
  unsigned short g2 = f2bf(x2 - bf2f(h2)), g3 = f2bf(x3 - bf2f(h3));
  *(uint2*)(Vhi + (size_t)(j0 + rr) * 128 + cc) =
      make_uint2((unsigned)h0 | ((unsigned)h1 << 16), (unsigned)h2 | ((unsigned)h3 << 16));
  *(uint2*)(Vlo + (size_t)(j0 + rr) * 128 + cc) =
      make_uint2((unsigned)g0 | ((unsigned)g1 << 16), (unsigned)g2 | ((unsigned)g3 << 16));
}

// ---------------- MFMA pair phase: 16 q x 64 j per wave, 4 waves merged in-block ----------------
__launch_bounds__(256, 2)
__global__ void attn_mfma(const unsigned short* __restrict__ Qhi, const unsigned short* __restrict__ Qlo,
                          const unsigned short* __restrict__ Khi, const unsigned short* __restrict__ Klo,
                          const unsigned short* __restrict__ Vhi, const unsigned short* __restrict__ Vlo,
                          const unsigned short* __restrict__ VThi, const unsigned short* __restrict__ VTlo,
                          const float* __restrict__ qt, const float* __restrict__ lqv,
                          const float* __restrict__ kt, const float* __restrict__ vt,
                          const float* __restrict__ lv, float* __restrict__ part) {
  int tid = threadIdx.x, wv = tid >> 6, lane = tid & 63;
  int l15 = lane & 15, lh = lane >> 4;
  int qg = blockIdx.x >> 3, sp = blockIdx.x & 7;
  int q0 = qg * 16;
  int j0 = sp * 256 + wv * 64;

  __shared__ __align__(16) unsigned short ghA[4][1024];
  __shared__ __align__(16) unsigned short glA[4][1024];
  __shared__ __align__(16) float mergeO[4][16][132];
  __shared__ float mergeS[4][3][16];

  // Q fragments (A-layout: row=lane&15, k=(lane>>4)*8+i)
  bf8_t qfh[4], qfl[4];
  {
    const unsigned short* qp = Qhi + (size_t)(q0 + l15) * 128 + lh * 8;
    const unsigned short* ql = Qlo + (size_t)(q0 + l15) * 128 + lh * 8;
#pragma unroll
    for (int ks = 0; ks < 4; ++ks) { qfh[ks] = ld8(qp + ks * 32); qfl[ks] = ld8(ql + ks * 32); }
  }
  float qtr[4], lq2[4];
#pragma unroll
  for (int r = 0; r < 4; ++r) {
    int q = q0 + lh * 4 + r;
    qtr[r] = qt[q];
    lq2[r] = 2.0f + lqv[q];
  }
  float ktj[4], vtj[4], lvj[4];
#pragma unroll
  for (int n = 0; n < 4; ++n) {
    int j = j0 + n * 16 + l15;
    ktj[n] = kt[j]; vtj[n] = vt[j]; lvj[n] = lv[j];
  }

  // ---- S/C phase: S = Q·K_spatial^T, C = Q·V_spatial^T (hi-lo, 3 passes) ----
  f32x4 sf[4], cf[4];
#pragma unroll
  for (int n = 0; n < 4; ++n) {
    f32x4 s = {0, 0, 0, 0}, c = {0, 0, 0, 0};
    size_t jrow = (size_t)(j0 + n * 16 + l15) * 128 + lh * 8;
    const unsigned short* kh = Khi + jrow;
    const unsigned short* kl = Klo + jrow;
    const unsigned short* vh = Vhi + jrow;
    const unsigned short* vl = Vlo + jrow;
#pragma unroll
    for (int ks = 0; ks < 4; ++ks) {
      bf8_t bkh = ld8(kh + ks * 32), bkl = ld8(kl + ks * 32);
      s = mfma16(qfh[ks], bkh, s);
      s = mfma16(qfh[ks], bkl, s);
      s = mfma16(qfl[ks], bkh, s);
      bf8_t bvh = ld8(vh + ks * 32), bvl = ld8(vl + ks * 32);
      c = mfma16(qfh[ks], bvh, c);
      c = mfma16(qfh[ks], bvl, c);
      c = mfma16(qfl[ks], bvh, c);
    }
    sf[n] = s; cf[n] = c;
  }

  // ---- elementwise: e, g; write g hi/lo to swizzled LDS ----
  float lsum[4] = {0, 0, 0, 0}, tcs[4] = {0, 0, 0, 0}, tts[4] = {0, 0, 0, 0};
#pragma unroll
  for (int n = 0; n < 4; ++n) {
#pragma unroll
    for (int r = 0; r < 4; ++r) {
      float sim = sf[n][r] - qtr[r] * ktj[n];
      float c = cf[n][r] - qtr[r] * vtj[n];
      float e = expf(-BETA_F * sim);              // logits in [0.09, 48]: no overflow
      float z = fmaxf(-c, 1.0f + EPSF);
      float dist = acoshf(z);
      float den2 = fmaxf(lvj[n] + lq2[r] * c * c, EPSF);
      float g = e * dist * rsqrtf(den2);
      lsum[r] += e;
      tcs[r] += g * c;
      tts[r] += g * vtj[n];
      unsigned short gh = f2bf(g);
      unsigned short gl = f2bf(g - bf2f(gh));
      int q_ = lh * 4 + r;
      int idx = (q_ * 64 + n * 16 + l15) ^ ((q_ & 7) << 3);
      ghA[wv][idx] = gh;
      glA[wv][idx] = gl;
    }
  }
  asm volatile("s_waitcnt lgkmcnt(0)" ::: "memory");
  __builtin_amdgcn_sched_barrier(0);

  // ---- O phase: O += G · V  (A = G from LDS, B = V^T[d][j]) ----
  f32x4 accO[8];
#pragma unroll
  for (int dn = 0; dn < 8; ++dn) accO[dn] = f32x4{0, 0, 0, 0};
#pragma unroll
  for (int jk = 0; jk < 2; ++jk) {
    int base = (l15 * 64 + jk * 32 + lh * 8) ^ ((l15 & 7) << 3);
    bf8_t ah = ld8(&ghA[wv][base]);
    bf8_t al = ld8(&glA[wv][base]);
#pragma unroll
    for (int dn = 0; dn < 8; ++dn) {
      size_t vrow = (size_t)(dn * 16 + l15) * 2048 + j0 + jk * 32 + lh * 8;
      bf8_t bh = ld8(VThi + vrow), bl = ld8(VTlo + vrow);
      accO[dn] = mfma16(ah, bh, accO[dn]);
      accO[dn] = mfma16(ah, bl, accO[dn]);
      accO[dn] = mfma16(al, bh, accO[dn]);
    }
  }

  // ---- reduce row scalars across the 16-lane column groups ----
#pragma unroll
  for (int r = 0; r < 4; ++r) {
#pragma unroll
    for (int off = 1; off < 16; off <<= 1) {
      lsum[r] += __shfl_xor(lsum[r], off);
      tcs[r] += __shfl_xor(tcs[r], off);
      tts[r] += __shfl_xor(tts[r], off);
    }
  }

  // ---- stash per-wave results to LDS for cross-wave merge ----
#pragma unroll
  for (int r = 0; r < 4; ++r) {
    int q_ = lh * 4 + r;
#pragma unroll
    for (int dn = 0; dn < 8; ++dn) mergeO[wv][q_][dn * 16 + l15] = accO[dn][r];
    if (l15 == 0) {
      mergeS[wv][0][q_] = lsum[r];
      mergeS[wv][1][q_] = tcs[r];
      mergeS[wv][2][q_] = tts[r];
    }
  }
  __syncthreads();

  // ---- cross-wave merge (4 waves cover different j slices, same q) ----
#pragma unroll
  for (int e = 0; e < 2; ++e) {
    int t = tid + e * 256;        // [0,512): 512 float4 chunks = 16 q x 32 chunks
    int q_ = t >> 5, d0 = (t & 31) * 4;
    float4 s = make_float4(0.f, 0.f, 0.f, 0.f);
#pragma unroll
    for (int w = 0; w < 4; ++w) {
      float4 v = *(const float4*)&mergeO[w][q_][d0];
      s.x += v.x; s.y += v.y; s.z += v.z; s.w += v.w;
    }
    float* P = part + ((size_t)(q0 + q_) * 8 + sp) * 132;
    *(float4*)(P + d0) = s;
  }
  if (tid < 16) {
    int q_ = tid;
    float a = 0, b = 0, cc2 = 0;
#pragma unroll
    for (int w = 0; w < 4; ++w) {
      a += mergeS[w][0][q_];
      b += mergeS[w][1][q_];
      cc2 += mergeS[w][2][q_];
    }
    float* P = part + ((size_t)(q0 + q_) * 8 + sp) * 132;
    P[128] = a; P[129] = b; P[130] = cc2;
  }
}

// ---------------- merge splits + hyperbolic epilogue ----------------
__global__ void merge_fin(const float* __restrict__ part, const float* __restrict__ Qs,
                          const float* __restrict__ qt, float* __restrict__ out) {
  int qi = blockIdx.x;
  int lane = threadIdx.x;  // 64
  const float* P = part + (size_t)qi * 8 * 132;
  float ox = 0, oy = 0, l = 0, tc = 0, tt = 0;
#pragma unroll
  for (int s = 0; s < 8; ++s) {
    const float* p = P + s * 132;
    float2 o2 = *(const float2*)(p + 2 * lane);
    ox += o2.x; oy += o2.y;
    l += p[128]; tc += p[129]; tt += p[130];
  }
  float2 q2 = ((const float2*)(Qs + (size_t)qi * 128))[lane];
  float qtv = qt[qi];
  float invl = 1.0f / l;
  float Tmx = (ox + tc * q2.x) * invl;
  float Tmy = (oy + tc * q2.y) * invl;
  float Tmt = (tt + tc * qtv) * invl;
  float sp2 = wave_sum(Tmx * Tmx + Tmy * Tmy);
  float LT = sp2 - Tmt * Tmt;
  float un = sqrtf(fmaxf(LT, EPSF));
  float ch = coshf(un);
  float shv = sinhf(un) / un;
  float zx = ch * q2.x + shv * Tmx;
  float zy = ch * q2.y + shv * Tmy;
  float zt = ch * qtv + shv * Tmt;
  float zn2 = wave_sum(zx * zx + zy * zy);
  float nz = fmaxf(sqrtf(zn2), EPSF);
  float dist = acoshf(fmaxf(zt, 1.0f + EPSF));
  float sc = dist / nz;
  ((float2*)(out + (size_t)qi * 128))[lane] = make_float2(sc * zx, sc * zy);
}

extern "C" void kernel_launch(void* const* d_in, const int* in_sizes, int n_in,
                              void* d_out, int out_size, void* d_ws, size_t ws_size,
                              hipStream_t stream) {
  const float* queries = (const float*)d_in[0];
  const float* keys = (const float*)d_in[1];
  const float* values = (const float*)d_in[2];
  const float* WK = (const float*)d_in[3];
  const float* WV = (const float*)d_in[4];
  float* ws = (float*)d_ws;

  float* Qs = ws + WS_QS;
  float* qt_ = ws + WS_QT;
  float* lq_ = ws + WS_LQ;
  float* kt_ = ws + WS_KT;
  float* vt_ = ws + WS_VT;
  float* lv_ = ws + WS_LV;
  unsigned short* Qhi = (unsigned short*)(ws + WS_QHI);
  unsigned short* Qlo = (unsigned short*)(ws + WS_QLO);
  unsigned short* Khi = (unsigned short*)(ws + WS_KHI);
  unsigned short* Klo = (unsigned short*)(ws + WS_KLO);
  unsigned short* Vhi = (unsigned short*)(ws + WS_VHI);
  unsigned short* Vlo = (unsigned short*)(ws + WS_VLO);
  unsigned short* VThi = (unsigned short*)(ws + WS_VTHI);
  unsigned short* VTlo = (unsigned short*)(ws + WS_VTLO);
  float* part = ws + WS_PART;
  float* out = (float*)d_out;

  prep_q<<<1024, 64, 0, stream>>>(queries, Qs, qt_, lq_, (unsigned int*)Qhi, (unsigned int*)Qlo);
  prep_k<<<512, 128, 0, stream>>>(keys, WK, Khi, Klo, kt_);
  prep_v<<<512, 128, 0, stream>>>(values, WK, WV, Vhi, Vlo, VThi, VTlo, vt_, lv_);
  attn_mfma<<<512, 256, 0, stream>>>(Qhi, Qlo, Khi, Klo, Vhi, Vlo, VThi, VTlo,
                                     qt_, lq_, kt_, vt_, lv_, part);
  merge_fin<<<1024, 64, 0, stream>>>(part, Qs, qt_, out);
}